// Round 2
// baseline (76.006 us; speedup 1.0000x reference)
//
#include <hip/hip_runtime.h>
#include <math.h>

#define N_BINS 360
#define VEC4_PER_ROW 90   // 360/4
#define GRID_BLOCKS 2048

// Fused: Gaussian-vs-pred squared error, per-block partials, last-ticket block
// does the deterministic f64 final reduce (no second launch).
__global__ void __launch_bounds__(256) emd_fused_kernel(
    const float* __restrict__ y_pred,
    const int*   __restrict__ y_labels,
    float*       __restrict__ partials,
    unsigned int* __restrict__ counter,
    float*       __restrict__ out,
    int total_vec4,
    float invB)
{
    const float norm   = 0.07978845608028654f;  // 1/(sqrt(2*pi)*5)
    const float inv2s2 = 0.02f;                 // 1/(2*sigma^2), sigma=5

    float acc = 0.0f;
    const int stride = gridDim.x * blockDim.x;
    const float4* __restrict__ pred4 = reinterpret_cast<const float4*>(y_pred);

    for (int f = blockIdx.x * blockDim.x + threadIdx.x; f < total_vec4; f += stride) {
        const int row = f / VEC4_PER_ROW;                 // magic-mul div
        const int b0  = (f - row * VEC4_PER_ROW) * 4;
        const float lbl = (float)y_labels[row];

        const float4 p = pred4[f];
        const float pv[4] = {p.x, p.y, p.z, p.w};
        const float tbase = (float)b0 - lbl;
        #pragma unroll
        for (int j = 0; j < 4; ++j) {
            const float t = tbase + (float)j;
            const float e = __expf(-t * t * inv2s2) * norm;  // v_exp_f32
            const float d = e - pv[j];
            acc = fmaf(d, d, acc);
        }
    }

    // 64-lane butterfly reduce
    #pragma unroll
    for (int off = 32; off > 0; off >>= 1)
        acc += __shfl_down(acc, off, 64);

    __shared__ float wsum[4];
    __shared__ int lastFlag;
    const int wave = threadIdx.x >> 6;
    const int lane = threadIdx.x & 63;
    if (lane == 0) wsum[wave] = acc;
    __syncthreads();

    if (threadIdx.x == 0) {
        const float blocksum = wsum[0] + wsum[1] + wsum[2] + wsum[3];
        // device-scope store of this block's partial, then release via ticket
        __hip_atomic_store(&partials[blockIdx.x], blocksum,
                           __ATOMIC_RELAXED, __HIP_MEMORY_SCOPE_AGENT);
        const unsigned prev = __hip_atomic_fetch_add(counter, 1u,
                           __ATOMIC_ACQ_REL, __HIP_MEMORY_SCOPE_AGENT);
        lastFlag = (prev == gridDim.x - 1) ? 1 : 0;
    }
    __syncthreads();

    if (lastFlag) {
        // All prior partial stores are ordered before our acquiring ticket read.
        double a = 0.0;
        for (int i = threadIdx.x; i < (int)gridDim.x; i += blockDim.x)
            a += (double)__hip_atomic_load(&partials[i],
                           __ATOMIC_RELAXED, __HIP_MEMORY_SCOPE_AGENT);

        __shared__ double sd[256];
        sd[threadIdx.x] = a;
        __syncthreads();
        #pragma unroll
        for (int s = 128; s > 0; s >>= 1) {
            if (threadIdx.x < s) sd[threadIdx.x] += sd[threadIdx.x + s];
            __syncthreads();
        }
        if (threadIdx.x == 0)
            out[0] = (float)(sd[0] * (double)invB);
    }
}

extern "C" void kernel_launch(void* const* d_in, const int* in_sizes, int n_in,
                              void* d_out, int out_size, void* d_ws, size_t ws_size,
                              hipStream_t stream)
{
    const float* y_pred   = (const float*)d_in[0];
    const int*   y_labels = (const int*)d_in[1];
    float* out = (float*)d_out;

    const int B = in_sizes[1];                 // 65536
    const int total_vec4 = B * VEC4_PER_ROW;   // 5,898,240

    float* partials = (float*)d_ws;
    unsigned int* counter = (unsigned int*)((char*)d_ws + GRID_BLOCKS * sizeof(float));

    // Zero the ticket counter every call (d_ws is poisoned once, never restored).
    hipMemsetAsync(counter, 0, sizeof(unsigned int), stream);

    emd_fused_kernel<<<GRID_BLOCKS, 256, 0, stream>>>(
        y_pred, y_labels, partials, counter, out,
        total_vec4, 1.0f / (float)B);
}

// Round 3
// 47.046 us; speedup vs baseline: 1.6156x; 1.6156x over previous
//
#include <hip/hip_runtime.h>
#include <math.h>

#define N_BINS 360
#define GROUPS_PER_ROW 45   // 360 bins / 8 floats per group
#define GRID_BLOCKS 2048    // 8 blocks/CU x 256 CU = exact machine fill

// Gaussian-vs-pred squared error. Each thread consumes 32B (two float4s) per
// iteration. Per-block partial is folded into d_out via ONE relaxed f32
// atomicAdd (no acquire/release -> no buffer_wbl2/buffer_inv L2 thrash).
__global__ void __launch_bounds__(256) emd_main_kernel(
    const float* __restrict__ y_pred,
    const int*   __restrict__ y_labels,
    float*       __restrict__ out,
    int total_groups,
    float invB)
{
    const float norm   = 0.07978845608028654f;  // 1/(sqrt(2*pi)*5)
    const float inv2s2 = 0.02f;                 // 1/(2*sigma^2), sigma=5

    float acc = 0.0f;
    const int stride = gridDim.x * blockDim.x;
    const float4* __restrict__ pred4 = reinterpret_cast<const float4*>(y_pred);

    for (int g = blockIdx.x * blockDim.x + threadIdx.x; g < total_groups; g += stride) {
        const int row = g / GROUPS_PER_ROW;             // magic-mul div
        const int b0  = (g - row * GROUPS_PER_ROW) * 8; // starting bin
        const float lbl = (float)y_labels[row];

        const float4 pa = pred4[2 * g];
        const float4 pb = pred4[2 * g + 1];
        const float pv[8] = {pa.x, pa.y, pa.z, pa.w, pb.x, pb.y, pb.z, pb.w};
        const float tbase = (float)b0 - lbl;

        #pragma unroll
        for (int j = 0; j < 8; ++j) {
            const float t = tbase + (float)j;
            const float e = __expf(-t * t * inv2s2) * norm;  // v_exp_f32
            const float d = e - pv[j];
            acc = fmaf(d, d, acc);
        }
    }

    // 64-lane butterfly reduce
    #pragma unroll
    for (int off = 32; off > 0; off >>= 1)
        acc += __shfl_down(acc, off, 64);

    __shared__ float wsum[4];
    const int lane = threadIdx.x & 63;
    if (lane == 0) wsum[threadIdx.x >> 6] = acc;
    __syncthreads();

    if (threadIdx.x == 0) {
        const float blocksum = (wsum[0] + wsum[1] + wsum[2] + wsum[3]) * invB;
        atomicAdd(out, blocksum);   // relaxed, device-scope, no cache maintenance
    }
}

extern "C" void kernel_launch(void* const* d_in, const int* in_sizes, int n_in,
                              void* d_out, int out_size, void* d_ws, size_t ws_size,
                              hipStream_t stream)
{
    const float* y_pred   = (const float*)d_in[0];
    const int*   y_labels = (const int*)d_in[1];
    float* out = (float*)d_out;

    const int B = in_sizes[1];                    // 65536
    const int total_groups = B * GROUPS_PER_ROW;  // 2,949,120

    // d_out is poisoned (0xAA) once and never re-poisoned; zero it every call
    // so the per-block atomicAdds accumulate from a clean slate each replay.
    hipMemsetAsync(out, 0, sizeof(float), stream);

    emd_main_kernel<<<GRID_BLOCKS, 256, 0, stream>>>(
        y_pred, y_labels, out, total_groups, 1.0f / (float)B);
}

// Round 4
// 21.661 us; speedup vs baseline: 3.5088x; 2.1719x over previous
//
#include <hip/hip_runtime.h>
#include <math.h>

#define N_BINS 360
#define GROUPS_PER_ROW 45   // 360 bins / 8 floats per group
#define GRID_BLOCKS 2048    // 8 blocks/CU x 256 CU = exact machine fill
#define FINAL_WAVE 64

// Kernel 1: Gaussian-vs-pred squared error. 32B (two float4) per thread-iter.
// One plain f32 partial store per block — no atomics, no fences.
__global__ void __launch_bounds__(256) emd_partial_kernel(
    const float* __restrict__ y_pred,
    const int*   __restrict__ y_labels,
    float*       __restrict__ partials,
    int total_groups)
{
    const float norm   = 0.07978845608028654f;  // 1/(sqrt(2*pi)*5)
    const float inv2s2 = 0.02f;                 // 1/(2*sigma^2), sigma=5

    float acc = 0.0f;
    const int stride = gridDim.x * blockDim.x;
    const float4* __restrict__ pred4 = reinterpret_cast<const float4*>(y_pred);

    for (int g = blockIdx.x * blockDim.x + threadIdx.x; g < total_groups; g += stride) {
        const int row = g / GROUPS_PER_ROW;             // magic-mul div
        const int b0  = (g - row * GROUPS_PER_ROW) * 8; // starting bin
        const float lbl = (float)y_labels[row];

        const float4 pa = pred4[2 * g];
        const float4 pb = pred4[2 * g + 1];
        const float pv[8] = {pa.x, pa.y, pa.z, pa.w, pb.x, pb.y, pb.z, pb.w};
        const float tbase = (float)b0 - lbl;

        #pragma unroll
        for (int j = 0; j < 8; ++j) {
            const float t = tbase + (float)j;
            const float e = __expf(-t * t * inv2s2) * norm;  // v_exp_f32
            const float d = e - pv[j];
            acc = fmaf(d, d, acc);
        }
    }

    // 64-lane butterfly reduce
    #pragma unroll
    for (int off = 32; off > 0; off >>= 1)
        acc += __shfl_down(acc, off, 64);

    __shared__ float wsum[4];
    const int lane = threadIdx.x & 63;
    if (lane == 0) wsum[threadIdx.x >> 6] = acc;
    __syncthreads();

    if (threadIdx.x == 0)
        partials[blockIdx.x] = wsum[0] + wsum[1] + wsum[2] + wsum[3];
}

// Kernel 2: one wave, f64 accumulate of 2048 partials, butterfly, write scalar.
// Plain store to out[0] every call -> no pre-zero of d_out needed, and no
// hipMemsetAsync graph node (round 3 showed a 4-byte fill costs ~25-30 us!).
__global__ void __launch_bounds__(FINAL_WAVE) emd_final_kernel(
    const float* __restrict__ partials,
    float* __restrict__ out,
    double invB)
{
    const int lane = threadIdx.x;  // 0..63
    double a = 0.0;
    #pragma unroll
    for (int k = 0; k < GRID_BLOCKS / FINAL_WAVE; ++k)
        a += (double)partials[lane + FINAL_WAVE * k];

    #pragma unroll
    for (int off = 32; off > 0; off >>= 1)
        a += __shfl_down(a, off, 64);

    if (lane == 0)
        out[0] = (float)(a * invB);
}

extern "C" void kernel_launch(void* const* d_in, const int* in_sizes, int n_in,
                              void* d_out, int out_size, void* d_ws, size_t ws_size,
                              hipStream_t stream)
{
    const float* y_pred   = (const float*)d_in[0];
    const int*   y_labels = (const int*)d_in[1];
    float* out = (float*)d_out;

    const int B = in_sizes[1];                    // 65536
    const int total_groups = B * GROUPS_PER_ROW;  // 2,949,120

    float* partials = (float*)d_ws;

    emd_partial_kernel<<<GRID_BLOCKS, 256, 0, stream>>>(
        y_pred, y_labels, partials, total_groups);
    emd_final_kernel<<<1, FINAL_WAVE, 0, stream>>>(
        partials, out, 1.0 / (double)B);
}

// Round 6
// 21.450 us; speedup vs baseline: 3.5434x; 1.0099x over previous
//
#include <hip/hip_runtime.h>
#include <math.h>

#define N_BINS 360
#define GROUPS_PER_ROW 45     // 360 bins / 8 floats per group
#define GRID_BLOCKS 512       // 512 blocks x 1024 thr = 2 blocks/CU x 16 waves = 32 waves/CU
#define BLOCK_THREADS 1024
#define FINAL_WAVE 64

// Kernel 1: Gaussian-vs-pred squared error. 32B (two float4) per thread-iter,
// grid-stride (fine-grained -> balanced tail). One plain f32 partial per block.
__global__ void __launch_bounds__(BLOCK_THREADS, 8) emd_partial_kernel(
    const float* __restrict__ y_pred,
    const int*   __restrict__ y_labels,
    float*       __restrict__ partials,
    int total_groups)
{
    const float norm = 0.07978845608028654f;   // 1/(sqrt(2*pi)*5)
    // exp(-t^2/(2*25)) = exp2(-t^2 * 0.02 * log2(e)); v_exp_f32 IS exp2.
    const float c2   = 0.028853900817779268f;  // 0.02 * 1.4426950408889634

    float acc = 0.0f;
    const int stride = gridDim.x * blockDim.x;
    const float4* __restrict__ pred4 = reinterpret_cast<const float4*>(y_pred);

    for (int g = blockIdx.x * blockDim.x + threadIdx.x; g < total_groups; g += stride) {
        const int row = g / GROUPS_PER_ROW;             // magic-mul div
        const int b0  = (g - row * GROUPS_PER_ROW) * 8; // starting bin
        const float lbl = (float)y_labels[row];

        const float4 pa = pred4[2 * g];
        const float4 pb = pred4[2 * g + 1];
        const float pv[8] = {pa.x, pa.y, pa.z, pa.w, pb.x, pb.y, pb.z, pb.w};
        const float tbase = (float)b0 - lbl;

        #pragma unroll
        for (int j = 0; j < 8; ++j) {
            const float t = tbase + (float)j;
            const float e = __builtin_amdgcn_exp2f(-(t * t) * c2) * norm;  // v_exp_f32
            const float d = e - pv[j];
            acc = fmaf(d, d, acc);
        }
    }

    // 64-lane butterfly reduce
    #pragma unroll
    for (int off = 32; off > 0; off >>= 1)
        acc += __shfl_down(acc, off, 64);

    __shared__ float wsum[BLOCK_THREADS / 64];
    const int lane = threadIdx.x & 63;
    if (lane == 0) wsum[threadIdx.x >> 6] = acc;
    __syncthreads();

    if (threadIdx.x == 0) {
        float s = 0.0f;
        #pragma unroll
        for (int w = 0; w < BLOCK_THREADS / 64; ++w) s += wsum[w];
        partials[blockIdx.x] = s;
    }
}

// Kernel 2: one wave, 512 partials as 2 coalesced float4 loads/lane,
// f64 accumulate + butterfly, plain store of the scalar (no zero-init needed).
__global__ void __launch_bounds__(FINAL_WAVE) emd_final_kernel(
    const float* __restrict__ partials,
    float* __restrict__ out,
    double invB)
{
    const int lane = threadIdx.x;  // 0..63
    const float4* __restrict__ p4 = reinterpret_cast<const float4*>(partials);

    const float4 v0 = p4[lane];        // partials[0..255]
    const float4 v1 = p4[lane + 64];   // partials[256..511]

    double a = ((double)v0.x + (double)v0.y) + ((double)v0.z + (double)v0.w)
             + ((double)v1.x + (double)v1.y) + ((double)v1.z + (double)v1.w);

    #pragma unroll
    for (int off = 32; off > 0; off >>= 1)
        a += __shfl_down(a, off, 64);

    if (lane == 0)
        out[0] = (float)(a * invB);
}

extern "C" void kernel_launch(void* const* d_in, const int* in_sizes, int n_in,
                              void* d_out, int out_size, void* d_ws, size_t ws_size,
                              hipStream_t stream)
{
    const float* y_pred   = (const float*)d_in[0];
    const int*   y_labels = (const int*)d_in[1];
    float* out = (float*)d_out;

    const int B = in_sizes[1];                    // 65536
    const int total_groups = B * GROUPS_PER_ROW;  // 2,949,120

    float* partials = (float*)d_ws;               // 512 floats

    emd_partial_kernel<<<GRID_BLOCKS, BLOCK_THREADS, 0, stream>>>(
        y_pred, y_labels, partials, total_groups);
    emd_final_kernel<<<1, FINAL_WAVE, 0, stream>>>(
        partials, out, 1.0 / (double)B);
}